// Round 13
// baseline (2786.718 us; speedup 1.0000x reference)
//
#include <hip/hip_runtime.h>
#include <math.h>

#define BB 16
#define SS 32
#define DIN 8
#define DD 512
#define DOUTC 8
#define LLAYERS 4
#define HH 8
#define DFF 2048
#define DHH 64
#define TT 31       // positions produced (S-1)
#define NWG 256     // persistent grid: 256 WGs x 512 threads (2 waves/SIMD)
#define NT 512
#define XP 520      // padded stride for [4][512] LDS rows (float4-aligned)
#define XP2 264     // padded stride for [4][256]
#define KLS 65      // LDS row stride for attn K tile (conflict-free)
#define WOFF 4480   // LDS offset (floats) of the 64KB weight tile

// 4 independent batch-groups: group g = (wg>>3)&3 owns batches {g,g+4,g+8,g+12}.
// All mutable buffers are batch-indexed => zero cross-group sharing; each group
// has its own 64-arrival barrier and drifts freely.

struct P {
  const float *seq,*pe,*Wt,*bt,*Wq,*bq,*Wk,*bk,*Wv,*bv,*Wo,*bo,
              *ln1s,*ln1b,*W1,*b1,*W2,*b2,*ln2s,*ln2b,*Wf,*bf;
  float *Kc,*Vc,*qkvp,*f1p,*sA,*sB,*ln1x,*out;
  unsigned *bar;
};

#define KVIDX(l,b,j) ((((size_t)((l)*BB+(b)))*TT + (j)) * DD)

// ---------------------------------------------------------------------------
// Coherent (cache-bypassing, fabric-serialized) accessors. ALL mutable
// cross-WG data (including KV history) goes through these.
// ---------------------------------------------------------------------------
__device__ __forceinline__ float aload(const float* p) {
  return __hip_atomic_load(p, __ATOMIC_RELAXED, __HIP_MEMORY_SCOPE_AGENT);
}
__device__ __forceinline__ void astore(float* p, float v) {
  __hip_atomic_store(p, v, __ATOMIC_RELAXED, __HIP_MEMORY_SCOPE_AGENT);
}
__device__ __forceinline__ unsigned uload(const unsigned* p) {
  return __hip_atomic_load(p, __ATOMIC_RELAXED, __HIP_MEMORY_SCOPE_AGENT);
}

// ---------------------------------------------------------------------------
// Per-group split barrier: 64 arrivals over 8 spread counters (8 each).
// arrive() = syncthreads (drains vmcnt => stores at fabric) + 1 relaxed RMW.
// waitrnd(): lanes 0-7 read-poll the group's 8 counters. Zeroed at launch.
// ---------------------------------------------------------------------------
__device__ __forceinline__ void arrive(unsigned* bar, int g) {
  __syncthreads();
  if (threadIdx.x == 0)
    __hip_atomic_fetch_add(&bar[32 + (g*8 + (blockIdx.x & 7)) * 32], 1u,
                           __ATOMIC_RELAXED, __HIP_MEMORY_SCOPE_AGENT);
}
__device__ __forceinline__ void waitrnd(unsigned* bar, int g, unsigned rnd) {
  if (threadIdx.x < 8) {
    while (uload(&bar[32 + (g*8 + threadIdx.x) * 32]) < rnd * 8u)
      __builtin_amdgcn_s_sleep(1);
  }
  asm volatile("" ::: "memory");
  __syncthreads();
}

// ---------------------------------------------------------------------------
// Async global->LDS DMA, 16B/lane (global_load_lds_dwordx4).
// ---------------------------------------------------------------------------
__device__ __forceinline__ void g2l16(const float* g, float* l) {
  __builtin_amdgcn_global_load_lds(
      (const __attribute__((address_space(1))) void*)g,
      (__attribute__((address_space(3))) void*)l, 16, 0, 0);
}

// 256-row x 64-col fp32 tile (64KB) -> WL[256][64] linear. 8 waves.
__device__ __forceinline__ void stage_w(const float* gbase, size_t rstride,
                                        float* WL, int t) {
  const int wv = t >> 6, ln = t & 63;
  const int rr = ln >> 4, c4 = (ln & 15) * 4;
  const float* g0 = gbase + (size_t)rr * rstride + c4;
  for (int i = wv; i < 64; i += 8)
    g2l16(g0 + (size_t)(i * 4) * rstride, WL + i * 256);
}

// 64-row x 256-col fp32 tile (64KB) -> WL[64][256] linear (row stride DD).
__device__ __forceinline__ void stage_w64(const float* gbase, float* WL, int t) {
  const int wv = t >> 6, ln = t & 63;
  const float* g0 = gbase + ln * 4;
  for (int i = wv; i < 64; i += 8)
    g2l16(g0 + (size_t)i * DD, WL + i * 256);
}

// ---------------------------------------------------------------------------
// Group-local tile id: lid = (wg&7) + 8*(wg>>5) in [0,64). wg&7 = XCD residue
// (all replicas of a tile across groups share it -> tile lives in one L2).
// ---------------------------------------------------------------------------
__device__ __forceinline__ void dma_proj(const P& prm, int l, float* SH, int wg, int t) {
  const int lid = (wg & 7) + 8 * (wg >> 5);
  if (lid >= 48) return;
  const int cb = lid >> 1, kg = lid & 1;
  const int mat = cb >> 3, colb = cb & 7;
  const float* wbase = ((mat == 0) ? prm.Wq : (mat == 1) ? prm.Wk : prm.Wv)
                       + (size_t)l*DD*DD + (size_t)(kg*256)*DD + colb*64;
  stage_w(wbase, DD, SH + WOFF, t);
}
__device__ __forceinline__ void dma_attn(const P& prm, int l, float* SH, int wg, int t) {
  const int T16 = (wg & 7) + 8 * ((wg >> 5) & 1);
  const int h = T16 >> 1, ch = T16 & 1;
  stage_w64(prm.Wo + (size_t)l*DD*DD + (size_t)(h*DHH)*DD + ch*256, SH + WOFF, t);
}
__device__ __forceinline__ void dma_ffn1(const P& prm, int l, float* SH, int wg, int t) {
  const int lid = (wg & 7) + 8 * (wg >> 5);
  const int cb = lid >> 1, kg = lid & 1;
  stage_w(prm.W1 + (size_t)l*DD*DFF + (size_t)(kg*256)*DFF + cb*64, DFF, SH + WOFF, t);
}
__device__ __forceinline__ void dma_ffn2(const P& prm, int l, float* SH, int wg, int t) {
  const int lid = (wg & 7) + 8 * (wg >> 5);
  const int cb = lid >> 3, kg = lid & 7;
  stage_w(prm.W2 + (size_t)l*DFF*DD + (size_t)(kg*256)*DD + cb*64, DD, SH + WOFF, t);
}

// ---------------------------------------------------------------------------
// LN stats: X holds 4 rows at stride XP; first 4 waves -> one row each.
// ---------------------------------------------------------------------------
__device__ __forceinline__ void ln_stats4(const float* X, float* MV, int t) {
  if (t < 256) {
    int r = t >> 6, ln = t & 63;
    float s = 0.f, q = 0.f;
    for (int i = ln; i < DD; i += 64) { float v = X[r*XP + i]; s += v; q += v*v; }
#pragma unroll
    for (int m = 32; m >= 1; m >>= 1) { s += __shfl_xor(s, m); q += __shfl_xor(q, m); }
    if (ln == 0) {
      float mu = s * (1.f/DD);
      MV[r*2]   = mu;
      MV[r*2+1] = rsqrtf(fmaxf(q * (1.f/DD) - mu*mu, 0.f) + 1e-5f);
    }
  }
}

// ---------------------------------------------------------------------------
// PROJ (weights prefetched). Rows r=0..3 -> batch g+4r. X = LN2(sB) or
// head+embed. lid==0 publishes sA = x + bo and out row. 8-wave GEMM ->
// qkvp[kg] complete per (kg, batch, col).
// ---------------------------------------------------------------------------
__device__ __forceinline__ void proj_stage(const P& prm, int p, int l, float* SH) {
  const int wg = blockIdx.x, t = threadIdx.x;
  const int g = (wg >> 3) & 3;
  const int lid = (wg & 7) + 8 * (wg >> 5);
  if (lid >= 48) return;
  const int cb = lid >> 1, kg = lid & 1;
  const int mat = cb >> 3;
  float* X   = SH;            // 2080
  float* RED = SH + 2080;     // 2048
  float* YP  = SH + 4128;     // 256
  float* YS  = SH + 4384;     // 32
  float* MV  = SH + 4416;     // 8
  float* WL  = SH + WOFF;     // 16384

  if (l > 0 || p > 0) {
    for (int idx = t; idx < 4*DD; idx += NT) {
      int r = idx >> 9, i = idx & 511;
      X[r*XP + i] = aload(&prm.sB[(size_t)(g + 4*r)*DD + i]);
    }
    __syncthreads();
    ln_stats4(X, MV, t);
    __syncthreads();
    const int pl = (l > 0) ? (l - 1) : 3;
    const float* gm = prm.ln2s + pl*DD;
    const float* be = prm.ln2b + pl*DD;
    for (int idx = t; idx < 4*DD; idx += NT) {
      int r = idx >> 9, i = idx & 511;
      X[r*XP + i] = (X[r*XP + i] - MV[r*2]) * MV[r*2+1] * gm[i] + be[i];
    }
    __syncthreads();
  }
  if (l == 0) {
    if (p == 0) {
      if (t < 32) { int r = t>>3, c = t&7; YS[r*8 + c] = prm.seq[(size_t)(g + 4*r)*SS*DIN + c]; }
      __syncthreads();
    } else {
      if (t < 256) { // y = LN2_3(sB) @ Wf + bf (X holds LN'd rows)
        int r = t >> 6, oc = (t >> 3) & 7, ks = t & 7;
        float a = 0.f;
        const float* xr = X + r*XP + ks*64;
#pragma unroll 8
        for (int i = 0; i < 64; i++) a += xr[i] * prm.Wf[(ks*64 + i)*DOUTC + oc];
        YP[t] = a;
      }
      __syncthreads();
      if (t < 32) {
        int r = t>>3, oc = t&7;
        float yv = prm.bf[oc];
#pragma unroll
        for (int k = 0; k < 8; k++) yv += YP[r*64 + oc*8 + k];
        YS[r*8 + oc] = yv;
        if (lid == 0)
          prm.out[((size_t)(g + 4*r)*TT + (p-1))*DOUTC + oc] = yv;
      }
      __syncthreads();
    }
    for (int idx = t; idx < 4*DD; idx += NT) {
      int r = idx >> 9, i = idx & 511;
      float a = prm.bt[i] + prm.pe[(size_t)p*DD + i];
#pragma unroll
      for (int k = 0; k < 8; k++) a += YS[r*8 + k] * prm.Wt[k*DD + i];
      X[r*XP + i] = a;
    }
    __syncthreads();
  }
  if (lid == 0) {   // sA base = x + bo (attn atomically adds oproj)
    for (int idx = t; idx < 4*DD; idx += NT) {
      int r = idx >> 9, i = idx & 511;
      astore(&prm.sA[(size_t)(g + 4*r)*DD + i], X[r*XP + i] + prm.bo[l*DD + i]);
    }
  }
  // 8-wave GEMM from LDS: wave w -> K rows w*32..w*32+31 of the 256-row tile
  {
    const int w = t >> 6, lane = t & 63;
    const float* xb0 = X + 0*XP + kg*256 + w*32;
    const float* xb1 = X + 1*XP + kg*256 + w*32;
    const float* xb2 = X + 2*XP + kg*256 + w*32;
    const float* xb3 = X + 3*XP + kg*256 + w*32;
    const float* wl  = WL + (w*32)*64 + lane;
    float a0 = 0.f, a1 = 0.f, a2 = 0.f, a3 = 0.f;
#pragma unroll 4
    for (int kk = 0; kk < 32; kk += 4) {
      float4 x0 = *(const float4*)(xb0 + kk);
      float4 x1 = *(const float4*)(xb1 + kk);
      float4 x2 = *(const float4*)(xb2 + kk);
      float4 x3 = *(const float4*)(xb3 + kk);
      float w0 = wl[(kk+0)*64], w1 = wl[(kk+1)*64], w2 = wl[(kk+2)*64], w3 = wl[(kk+3)*64];
      a0 += x0.x*w0 + x0.y*w1 + x0.z*w2 + x0.w*w3;
      a1 += x1.x*w0 + x1.y*w1 + x1.z*w2 + x1.w*w3;
      a2 += x2.x*w0 + x2.y*w1 + x2.z*w2 + x2.w*w3;
      a3 += x3.x*w0 + x3.y*w1 + x3.z*w2 + x3.w*w3;
    }
    RED[w*256 +   0 + lane] = a0;
    RED[w*256 +  64 + lane] = a1;
    RED[w*256 + 128 + lane] = a2;
    RED[w*256 + 192 + lane] = a3;
  }
  __syncthreads();
  if (t < 256) {
    int m = t >> 6, lane = t & 63;
    float v = 0.f;
#pragma unroll
    for (int w = 0; w < 8; w++) v += RED[w*256 + m*64 + lane];
    astore(&prm.qkvp[(size_t)kg*(BB*1536) + (size_t)(g + 4*m)*1536 + mat*DD + (cb & 7)*64 + lane], v);
  }
}

// ---------------------------------------------------------------------------
// ATTN + fused O-proj (Wo tile prefetched). Reduce qkvp (+bias); ch==0 writes
// Kc/Vc[p]; K history staged to LDS via ALOAD (coalescing transform);
// V history read DIRECTLY per-thread (each V[j][d] consumed by exactly one
// thread -> staging was pure overhead). softmax -> ctx -> oproj (2-way
// K-split over 512 thr) -> atomicAdd sA. Zeroes sB group-locally.
// ---------------------------------------------------------------------------
__device__ __forceinline__ void attn_stage(const P& prm, int p, int l, float* SH) {
  const int wg = blockIdx.x, t = threadIdx.x;
  const int g = (wg >> 3) & 3;
  const int lid = (wg & 7) + 8 * (wg >> 5);
  const int T16 = (wg & 7) + 8 * ((wg >> 5) & 1);
  const int h = T16 >> 1, ch = T16 & 1;
  const int b = g + 4 * (wg >> 6);
  float* QV  = SH;           // 64
  float* KN  = SH + 64;      // 64
  float* VN  = SH + 128;     // 64
  float* CV  = SH + 192;     // 64
  float* AW  = SH + 256;     // 32
  float* LK  = SH + 288;     // 32*KLS (ends 2368)
  float* RED = SH + 288;     // 512 (reuses LK after ctx)
  float* WL2 = SH + WOFF;    // 64x256

  {  // group-local sB zero: 64 WGs x 32 = group's 4 batches x 512
    const int br = lid >> 4, chunk = lid & 15;
    if (t >= 256 && t < 288)
      astore(&prm.sB[(size_t)(g + 4*br)*DD + chunk*32 + (t-256)], 0.f);
  }
  if (t < 192) {
    int mat = t >> 6, d = t & 63;
    int gc = mat*DD + h*DHH + d;
    float v = aload(&prm.qkvp[(size_t)b*1536 + gc])
            + aload(&prm.qkvp[(size_t)BB*1536 + (size_t)b*1536 + gc])
            + ((mat == 0) ? prm.bq : (mat == 1) ? prm.bk : prm.bv)[l*DD + h*DHH + d];
    if (mat == 0) QV[d] = v;
    else if (mat == 1) { KN[d] = v; if (ch == 0) astore(&prm.Kc[KVIDX(l,b,p) + h*DHH + d], v); }
    else               { VN[d] = v; if (ch == 0) astore(&prm.Vc[KVIDX(l,b,p) + h*DHH + d], v); }
  }
  __syncthreads();
  for (int idx = t; idx < (p+1)*64; idx += NT) {
    int j = idx >> 6, d = idx & 63;
    LK[j*KLS + d] = (j < p) ? aload(&prm.Kc[KVIDX(l,b,j) + h*DHH + d]) : KN[d];
  }
  __syncthreads();
  if (t < 64) {
    int j = t;
    float sc = -1e30f;
    if (j <= p) {
      float s = 0.f;
#pragma unroll 16
      for (int d = 0; d < DHH; d++) s += QV[d] * LK[j*KLS + d];
      sc = s * 0.125f;  // 1/sqrt(64)
    }
    float mx = sc;
#pragma unroll
    for (int m = 32; m >= 1; m >>= 1) mx = fmaxf(mx, __shfl_xor(mx, m));
    float e = (j <= p) ? __expf(sc - mx) : 0.f;
    float den = e;
#pragma unroll
    for (int m = 32; m >= 1; m >>= 1) den += __shfl_xor(den, m);
    if (j < 32) AW[j] = (j <= p) ? (e / den) : 0.f;
  }
  __syncthreads();
  if (t < 64) {
    // ctx: V history read directly (coalesced aload per j); row p from VN.
    float a = AW[p] * VN[t];
    for (int j = 0; j < p; j++)
      a += AW[j] * aload(&prm.Vc[KVIDX(l,b,j) + h*DHH + t]);
    CV[t] = a;
  }
  __syncthreads();
  {  // oproj: col = ch*256 + (t&255), K half = t>>8 (32 each)
    const int c = t & 255, kh = t >> 8;
    const float* wp = WL2 + (kh*32)*256 + c;
    const float* cv = CV + kh*32;
    float a = 0.f;
#pragma unroll 8
    for (int k = 0; k < 32; k++) a += cv[k] * wp[k*256];
    RED[t] = a;
  }
  __syncthreads();
  if (t < 256)
    atomicAdd(&prm.sA[(size_t)b*DD + ch*256 + t], RED[t] + RED[t + 256]);
}

// ---------------------------------------------------------------------------
// FFN1 (W1 tile prefetched). X = LN1(sA); lid==0 publishes ln1x;
// 8-wave GEMM -> f1p[kg] via astore (deterministic, no atomics/zeroing).
// ---------------------------------------------------------------------------
__device__ __forceinline__ void ffn1_stage(const P& prm, int l, float* SH) {
  const int wg = blockIdx.x, t = threadIdx.x;
  const int g = (wg >> 3) & 3;
  const int lid = (wg & 7) + 8 * (wg >> 5);
  const int cb = lid >> 1, kg = lid & 1;
  float* X   = SH;            // 2080
  float* RED = SH + 2080;     // 2048
  float* MV  = SH + 4128;     // 8
  float* WL  = SH + WOFF;     // 16384
  for (int idx = t; idx < 4*DD; idx += NT) {
    int r = idx >> 9, i = idx & 511;
    X[r*XP + i] = aload(&prm.sA[(size_t)(g + 4*r)*DD + i]);
  }
  __syncthreads();
  ln_stats4(X, MV, t);
  __syncthreads();
  const float* gm = prm.ln1s + l*DD;
  const float* be = prm.ln1b + l*DD;
  for (int idx = t; idx < 4*DD; idx += NT) {
    int r = idx >> 9, i = idx & 511;
    X[r*XP + i] = (X[r*XP + i] - MV[r*2]) * MV[r*2+1] * gm[i] + be[i];
  }
  __syncthreads();
  if (lid == 0) {
    for (int idx = t; idx < 4*DD; idx += NT) {
      int r = idx >> 9, i = idx & 511;
      astore(&prm.ln1x[(size_t)(g + 4*r)*DD + i], X[r*XP + i]);
    }
  }
  {
    const int w = t >> 6, lane = t & 63;
    const float* xb0 = X + 0*XP + kg*256 + w*32;
    const float* xb1 = X + 1*XP + kg*256 + w*32;
    const float* xb2 = X + 2*XP + kg*256 + w*32;
    const float* xb3 = X + 3*XP + kg*256 + w*32;
    const float* wl  = WL + (w*32)*64 + lane;
    float a0 = 0.f, a1 = 0.f, a2 = 0.f, a3 = 0.f;
#pragma unroll 4
    for (int kk = 0; kk < 32; kk += 4) {
      float4 x0 = *(const float4*)(xb0 + kk);
      float4 x1 = *(const float4*)(xb1 + kk);
      float4 x2 = *(const float4*)(xb2 + kk);
      float4 x3 = *(const float4*)(xb3 + kk);
      float w0 = wl[(kk+0)*64], w1 = wl[(kk+1)*64], w2 = wl[(kk+2)*64], w3 = wl[(kk+3)*64];
      a0 += x0.x*w0 + x0.y*w1 + x0.z*w2 + x0.w*w3;
      a1 += x1.x*w0 + x1.y*w1 + x1.z*w2 + x1.w*w3;
      a2 += x2.x*w0 + x2.y*w1 + x2.z*w2 + x2.w*w3;
      a3 += x3.x*w0 + x3.y*w1 + x3.z*w2 + x3.w*w3;
    }
    RED[w*256 +   0 + lane] = a0;
    RED[w*256 +  64 + lane] = a1;
    RED[w*256 + 128 + lane] = a2;
    RED[w*256 + 192 + lane] = a3;
  }
  __syncthreads();
  if (t < 256) {
    int m = t >> 6, lane = t & 63;
    float v = 0.f;
#pragma unroll
    for (int w = 0; w < 8; w++) v += RED[w*256 + m*64 + lane];
    astore(&prm.f1p[(size_t)kg*(BB*DFF) + (size_t)(g + 4*m)*DFF + cb*64 + lane], v);
  }
}

// ---------------------------------------------------------------------------
// FFN2 (W2 tile prefetched). FX = relu(f1p0+f1p1+b1) chunk; 8-wave GEMM ->
// atomicAdd sB (+ln1x+b2 at kg==0).
// ---------------------------------------------------------------------------
__device__ __forceinline__ void ffn2_stage(const P& prm, int l, float* SH) {
  const int wg = blockIdx.x, t = threadIdx.x;
  const int g = (wg >> 3) & 3;
  const int lid = (wg & 7) + 8 * (wg >> 5);
  const int cb = lid >> 3, kg = lid & 7;
  float* FX  = SH;            // 4*XP2 = 1056
  float* RED = SH + 1056;     // 2048
  float* WL  = SH + WOFF;     // 16384
  for (int idx = t; idx < 4*256; idx += NT) {
    int r = idx >> 8, i = idx & 255;
    size_t off = (size_t)(g + 4*r)*DFF + kg*256 + i;
    FX[r*XP2 + i] = fmaxf(aload(&prm.f1p[off]) + aload(&prm.f1p[(size_t)BB*DFF + off])
                          + prm.b1[l*DFF + kg*256 + i], 0.f);
  }
  __syncthreads();
  {
    const int w = t >> 6, lane = t & 63;
    const float* x0p = FX + 0*XP2 + w*32;
    const float* x1p = FX + 1*XP2 + w*32;
    const float* x2p = FX + 2*XP2 + w*32;
    const float* x3p = FX + 3*XP2 + w*32;
    const float* wl  = WL + (w*32)*64 + lane;
    float a0 = 0.f, a1 = 0.f, a2 = 0.f, a3 = 0.f;
#pragma unroll 4
    for (int kk = 0; kk < 32; kk += 4) {
      float4 x0 = *(const float4*)(x0p + kk);
      float4 x1 = *(const float4*)(x1p + kk);
      float4 x2 = *(const float4*)(x2p + kk);
      float4 x3 = *(const float4*)(x3p + kk);
      float w0 = wl[(kk+0)*64], w1 = wl[(kk+1)*64], w2 = wl[(kk+2)*64], w3 = wl[(kk+3)*64];
      a0 += x0.x*w0 + x0.y*w1 + x0.z*w2 + x0.w*w3;
      a1 += x1.x*w0 + x1.y*w1 + x1.z*w2 + x1.w*w3;
      a2 += x2.x*w0 + x2.y*w1 + x2.z*w2 + x2.w*w3;
      a3 += x3.x*w0 + x3.y*w1 + x3.z*w2 + x3.w*w3;
    }
    RED[w*256 +   0 + lane] = a0;
    RED[w*256 +  64 + lane] = a1;
    RED[w*256 + 128 + lane] = a2;
    RED[w*256 + 192 + lane] = a3;
  }
  __syncthreads();
  if (t < 256) {
    int m = t >> 6, lane = t & 63;
    float v = 0.f;
#pragma unroll
    for (int w = 0; w < 8; w++) v += RED[w*256 + m*64 + lane];
    int c = cb*64 + lane;
    if (kg == 0) v += aload(&prm.ln1x[(size_t)(g + 4*m)*DD + c]) + prm.b2[l*DD + c];
    atomicAdd(&prm.sB[(size_t)(g + 4*m)*DD + c], v);
  }
}

// ---------------------------------------------------------------------------
// FINAL: out row 30 = LN2_3(sB)@Wf + bf. Per-group: lid<4 handles batch
// b = g + 4*lid (group-local — safe under drift).
// ---------------------------------------------------------------------------
__device__ __forceinline__ void final_stage(const P& prm) {
  const int wg = blockIdx.x, t = threadIdx.x;
  const int g = (wg >> 3) & 3;
  const int lid = (wg & 7) + 8 * (wg >> 5);
  if (lid >= 4 || t >= 64) return;
  const int b = g + 4*lid;
  float v[8];
  float s = 0.f, q = 0.f;
#pragma unroll
  for (int j = 0; j < 8; j++) {
    float x = aload(&prm.sB[(size_t)b*DD + t + j*64]);
    v[j] = x; s += x; q += x*x;
  }
#pragma unroll
  for (int m = 32; m >= 1; m >>= 1) { s += __shfl_xor(s, m); q += __shfl_xor(q, m); }
  const float mu = s * (1.f/DD);
  const float rs = rsqrtf(fmaxf(q * (1.f/DD) - mu*mu, 0.f) + 1e-5f);
  const float* gm = prm.ln2s + 3*DD;
  const float* be = prm.ln2b + 3*DD;
  float po[8];
#pragma unroll
  for (int oc = 0; oc < 8; oc++) po[oc] = 0.f;
#pragma unroll
  for (int j = 0; j < 8; j++) {
    const int i = t + j*64;
    const float x = (v[j] - mu) * rs * gm[i] + be[i];
#pragma unroll
    for (int oc = 0; oc < 8; oc++) po[oc] += x * prm.Wf[i*DOUTC + oc];
  }
#pragma unroll
  for (int m = 32; m >= 1; m >>= 1) {
#pragma unroll
    for (int oc = 0; oc < 8; oc++) po[oc] += __shfl_xor(po[oc], m);
  }
  if (t < 8) prm.out[((size_t)b*TT + 30)*DOUTC + t] = po[t] + prm.bf[t];
}

// ---------------------------------------------------------------------------
__global__ void __launch_bounds__(NT, 1) k_all(P prm) {
  __shared__ __align__(16) float SH[WOFF + 16384];   // 83.5 KB
  const int wg = blockIdx.x, t = threadIdx.x;
  const int g = (wg >> 3) & 3;
  unsigned rnd = 0;
  dma_proj(prm, 0, SH, wg, t);          // prefetch first proj weights
  for (int p = 0; p < TT; p++) {
    for (int l = 0; l < LLAYERS; l++) {
      proj_stage(prm, p, l, SH);
      arrive(prm.bar, g); dma_attn(prm, l, SH, wg, t); waitrnd(prm.bar, g, ++rnd);
      attn_stage(prm, p, l, SH);
      arrive(prm.bar, g); dma_ffn1(prm, l, SH, wg, t); waitrnd(prm.bar, g, ++rnd);
      ffn1_stage(prm, l, SH);
      arrive(prm.bar, g); dma_ffn2(prm, l, SH, wg, t); waitrnd(prm.bar, g, ++rnd);
      ffn2_stage(prm, l, SH);
      const int nl = (l < LLAYERS-1) ? l+1 : 0;
      arrive(prm.bar, g); dma_proj(prm, nl, SH, wg, t); waitrnd(prm.bar, g, ++rnd);
    }
  }
  final_stage(prm);
}

// ---------------------------------------------------------------------------
extern "C" void kernel_launch(void* const* d_in, const int* in_sizes, int n_in,
                              void* d_out, int out_size, void* d_ws, size_t ws_size,
                              hipStream_t stream) {
  (void)in_sizes; (void)n_in; (void)out_size; (void)ws_size;
  P prm;
  prm.seq  = (const float*)d_in[0];
  prm.pe   = (const float*)d_in[1];
  prm.Wt   = (const float*)d_in[2];
  prm.bt   = (const float*)d_in[3];
  prm.Wq   = (const float*)d_in[4];
  prm.bq   = (const float*)d_in[5];
  prm.Wk   = (const float*)d_in[6];
  prm.bk   = (const float*)d_in[7];
  prm.Wv   = (const float*)d_in[8];
  prm.bv   = (const float*)d_in[9];
  prm.Wo   = (const float*)d_in[10];
  prm.bo   = (const float*)d_in[11];
  prm.ln1s = (const float*)d_in[12];
  prm.ln1b = (const float*)d_in[13];
  prm.W1   = (const float*)d_in[14];
  prm.b1   = (const float*)d_in[15];
  prm.W2   = (const float*)d_in[16];
  prm.b2   = (const float*)d_in[17];
  prm.ln2s = (const float*)d_in[18];
  prm.ln2b = (const float*)d_in[19];
  prm.Wf   = (const float*)d_in[20];
  prm.bf   = (const float*)d_in[21];

  float* ws = (float*)d_ws;
  const size_t KSZ = (size_t)LLAYERS * BB * TT * DD;   // ~1.02M floats
  prm.Kc   = ws;
  prm.Vc   = prm.Kc   + KSZ;
  prm.qkvp = prm.Vc   + KSZ;                 // 2*16*1536 = 49152
  prm.f1p  = prm.qkvp + 2*BB*1536;           // 2*16*2048 = 65536
  prm.sA   = prm.f1p  + 2*(size_t)BB*DFF;    // 8192
  prm.sB   = prm.sA   + BB*DD;               // 8192
  prm.ln1x = prm.sB   + BB*DD;               // 8192
  prm.bar  = (unsigned*)(prm.ln1x + BB*DD);
  prm.out  = (float*)d_out;

  hipMemsetAsync((void*)prm.bar, 0, 8192, stream);
  hipLaunchKernelGGL(k_all, dim3(NWG), dim3(NT), 0, stream, prm);
}

// Round 14
// 2395.248 us; speedup vs baseline: 1.1634x; 1.1634x over previous
//
#include <hip/hip_runtime.h>
#include <math.h>

#define BB 16
#define SS 32
#define DIN 8
#define DD 512
#define DOUTC 8
#define LLAYERS 4
#define HH 8
#define DFF 2048
#define DHH 64
#define TT 31       // positions produced (S-1)
#define NWG 256     // persistent grid: 256 WGs x 512 threads (2 waves/SIMD)
#define NT 512
#define XP 520      // padded stride for [4][512] LDS rows (float4-aligned)
#define XP2 264     // padded stride for [4][256]
#define KLS 65      // LDS row stride for attn K/V tiles (conflict-free)
#define WOFF 4480   // LDS offset (floats) of the 64KB weight tile

// 4 independent batch-groups: group g = (wg>>3)&3 owns batches {g,g+4,g+8,g+12}.
// All mutable buffers are batch-indexed => zero cross-group sharing; each group
// has its own 64-arrival barrier and drifts freely.

struct P {
  const float *seq,*pe,*Wt,*bt,*Wq,*bq,*Wk,*bk,*Wv,*bv,*Wo,*bo,
              *ln1s,*ln1b,*W1,*b1,*W2,*b2,*ln2s,*ln2b,*Wf,*bf;
  float *Kc,*Vc,*qkvp,*sA,*sB,*ln1x,*f1,*out;
  unsigned *bar;
};

#define KVIDX(l,b,j) ((((size_t)((l)*BB+(b)))*TT + (j)) * DD)

// ---------------------------------------------------------------------------
// Coherent (cache-bypassing, fabric-serialized) accessors. ALL mutable
// cross-WG data (including KV history) goes through these.
// ---------------------------------------------------------------------------
__device__ __forceinline__ float aload(const float* p) {
  return __hip_atomic_load(p, __ATOMIC_RELAXED, __HIP_MEMORY_SCOPE_AGENT);
}
__device__ __forceinline__ void astore(float* p, float v) {
  __hip_atomic_store(p, v, __ATOMIC_RELAXED, __HIP_MEMORY_SCOPE_AGENT);
}
__device__ __forceinline__ unsigned uload(const unsigned* p) {
  return __hip_atomic_load(p, __ATOMIC_RELAXED, __HIP_MEMORY_SCOPE_AGENT);
}

// ---------------------------------------------------------------------------
// Per-group split barrier: 64 arrivals over 8 spread counters (8 each).
// arrive() = syncthreads (drains vmcnt => stores at fabric) + 1 relaxed RMW.
// waitrnd(): lanes 0-7 read-poll the group's 8 counters. Zeroed at launch.
// ---------------------------------------------------------------------------
__device__ __forceinline__ void arrive(unsigned* bar, int g) {
  __syncthreads();
  if (threadIdx.x == 0)
    __hip_atomic_fetch_add(&bar[32 + (g*8 + (blockIdx.x & 7)) * 32], 1u,
                           __ATOMIC_RELAXED, __HIP_MEMORY_SCOPE_AGENT);
}
__device__ __forceinline__ void waitrnd(unsigned* bar, int g, unsigned rnd) {
  if (threadIdx.x < 8) {
    while (uload(&bar[32 + (g*8 + threadIdx.x) * 32]) < rnd * 8u)
      __builtin_amdgcn_s_sleep(1);
  }
  asm volatile("" ::: "memory");
  __syncthreads();
}

// ---------------------------------------------------------------------------
// Async global->LDS DMA, 16B/lane (global_load_lds_dwordx4).
// ---------------------------------------------------------------------------
__device__ __forceinline__ void g2l16(const float* g, float* l) {
  __builtin_amdgcn_global_load_lds(
      (const __attribute__((address_space(1))) void*)g,
      (__attribute__((address_space(3))) void*)l, 16, 0, 0);
}

// 256-row x 64-col fp32 tile (64KB) -> WL[256][64] linear. 8 waves.
__device__ __forceinline__ void stage_w(const float* gbase, size_t rstride,
                                        float* WL, int t) {
  const int wv = t >> 6, ln = t & 63;
  const int rr = ln >> 4, c4 = (ln & 15) * 4;
  const float* g0 = gbase + (size_t)rr * rstride + c4;
  for (int i = wv; i < 64; i += 8)
    g2l16(g0 + (size_t)(i * 4) * rstride, WL + i * 256);
}

// 64-row x 256-col fp32 tile (64KB) -> WL[64][256] linear (row stride DD).
__device__ __forceinline__ void stage_w64(const float* gbase, float* WL, int t) {
  const int wv = t >> 6, ln = t & 63;
  const float* g0 = gbase + ln * 4;
  for (int i = wv; i < 64; i += 8)
    g2l16(g0 + (size_t)i * DD, WL + i * 256);
}

// ---------------------------------------------------------------------------
// Group-local tile id: lid = (wg&7) + 8*(wg>>5) in [0,64). wg&7 = XCD residue
// (all replicas of a tile across groups share it -> tile lives in one L2).
// ---------------------------------------------------------------------------
__device__ __forceinline__ void dma_proj(const P& prm, int l, float* SH, int wg, int t) {
  const int lid = (wg & 7) + 8 * (wg >> 5);
  if (lid >= 48) return;
  const int cb = lid >> 1, kg = lid & 1;
  const int mat = cb >> 3, colb = cb & 7;
  const float* wbase = ((mat == 0) ? prm.Wq : (mat == 1) ? prm.Wk : prm.Wv)
                       + (size_t)l*DD*DD + (size_t)(kg*256)*DD + colb*64;
  stage_w(wbase, DD, SH + WOFF, t);
}
__device__ __forceinline__ void dma_attn(const P& prm, int l, float* SH, int wg, int t) {
  const int T16 = (wg & 7) + 8 * ((wg >> 5) & 1);
  const int h = T16 >> 1, ch = T16 & 1;
  stage_w64(prm.Wo + (size_t)l*DD*DD + (size_t)(h*DHH)*DD + ch*256, SH + WOFF, t);
}
__device__ __forceinline__ void dma_ffn1(const P& prm, int l, float* SH, int wg, int t) {
  const int lid = (wg & 7) + 8 * (wg >> 5);
  const int cb = lid >> 1, kg = lid & 1;
  stage_w(prm.W1 + (size_t)l*DD*DFF + (size_t)(kg*256)*DFF + cb*64, DFF, SH + WOFF, t);
}
__device__ __forceinline__ void dma_ffn2(const P& prm, int l, float* SH, int wg, int t) {
  const int lid = (wg & 7) + 8 * (wg >> 5);
  const int cb = lid >> 3, kg = lid & 7;
  stage_w(prm.W2 + (size_t)l*DFF*DD + (size_t)(kg*256)*DD + cb*64, DD, SH + WOFF, t);
}

// ---------------------------------------------------------------------------
// LN stats: X holds 4 rows at stride XP; first 4 waves -> one row each.
// ---------------------------------------------------------------------------
__device__ __forceinline__ void ln_stats4(const float* X, float* MV, int t) {
  if (t < 256) {
    int r = t >> 6, ln = t & 63;
    float s = 0.f, q = 0.f;
    for (int i = ln; i < DD; i += 64) { float v = X[r*XP + i]; s += v; q += v*v; }
#pragma unroll
    for (int m = 32; m >= 1; m >>= 1) { s += __shfl_xor(s, m); q += __shfl_xor(q, m); }
    if (ln == 0) {
      float mu = s * (1.f/DD);
      MV[r*2]   = mu;
      MV[r*2+1] = rsqrtf(fmaxf(q * (1.f/DD) - mu*mu, 0.f) + 1e-5f);
    }
  }
}

// ---------------------------------------------------------------------------
// PROJ (weights prefetched). Rows r=0..3 -> batch g+4r. X = LN2(sB) or
// head+embed. lid==0 publishes sA = x + bo and out row. 8-wave GEMM ->
// qkvp[kg] complete per (kg, batch, col).
// ---------------------------------------------------------------------------
__device__ __forceinline__ void proj_stage(const P& prm, int p, int l, float* SH) {
  const int wg = blockIdx.x, t = threadIdx.x;
  const int g = (wg >> 3) & 3;
  const int lid = (wg & 7) + 8 * (wg >> 5);
  if (lid >= 48) return;
  const int cb = lid >> 1, kg = lid & 1;
  const int mat = cb >> 3;
  float* X   = SH;            // 2080
  float* RED = SH + 2080;     // 2048
  float* YP  = SH + 4128;     // 256
  float* YS  = SH + 4384;     // 32
  float* MV  = SH + 4416;     // 8
  float* WL  = SH + WOFF;     // 16384

  if (l > 0 || p > 0) {
    for (int idx = t; idx < 4*DD; idx += NT) {
      int r = idx >> 9, i = idx & 511;
      X[r*XP + i] = aload(&prm.sB[(size_t)(g + 4*r)*DD + i]);
    }
    __syncthreads();
    ln_stats4(X, MV, t);
    __syncthreads();
    const int pl = (l > 0) ? (l - 1) : 3;
    const float* gm = prm.ln2s + pl*DD;
    const float* be = prm.ln2b + pl*DD;
    for (int idx = t; idx < 4*DD; idx += NT) {
      int r = idx >> 9, i = idx & 511;
      X[r*XP + i] = (X[r*XP + i] - MV[r*2]) * MV[r*2+1] * gm[i] + be[i];
    }
    __syncthreads();
  }
  if (l == 0) {
    if (p == 0) {
      if (t < 32) { int r = t>>3, c = t&7; YS[r*8 + c] = prm.seq[(size_t)(g + 4*r)*SS*DIN + c]; }
      __syncthreads();
    } else {
      if (t < 256) { // y = LN2_3(sB) @ Wf + bf (X holds LN'd rows)
        int r = t >> 6, oc = (t >> 3) & 7, ks = t & 7;
        float a = 0.f;
        const float* xr = X + r*XP + ks*64;
#pragma unroll 8
        for (int i = 0; i < 64; i++) a += xr[i] * prm.Wf[(ks*64 + i)*DOUTC + oc];
        YP[t] = a;
      }
      __syncthreads();
      if (t < 32) {
        int r = t>>3, oc = t&7;
        float yv = prm.bf[oc];
#pragma unroll
        for (int k = 0; k < 8; k++) yv += YP[r*64 + oc*8 + k];
        YS[r*8 + oc] = yv;
        if (lid == 0)
          prm.out[((size_t)(g + 4*r)*TT + (p-1))*DOUTC + oc] = yv;
      }
      __syncthreads();
    }
    for (int idx = t; idx < 4*DD; idx += NT) {
      int r = idx >> 9, i = idx & 511;
      float a = prm.bt[i] + prm.pe[(size_t)p*DD + i];
#pragma unroll
      for (int k = 0; k < 8; k++) a += YS[r*8 + k] * prm.Wt[k*DD + i];
      X[r*XP + i] = a;
    }
    __syncthreads();
  }
  if (lid == 0) {   // sA base = x + bo (attn atomically adds oproj)
    for (int idx = t; idx < 4*DD; idx += NT) {
      int r = idx >> 9, i = idx & 511;
      astore(&prm.sA[(size_t)(g + 4*r)*DD + i], X[r*XP + i] + prm.bo[l*DD + i]);
    }
  }
  // 8-wave GEMM from LDS: wave w -> K rows w*32..w*32+31 of the 256-row tile
  {
    const int w = t >> 6, lane = t & 63;
    const float* xb0 = X + 0*XP + kg*256 + w*32;
    const float* xb1 = X + 1*XP + kg*256 + w*32;
    const float* xb2 = X + 2*XP + kg*256 + w*32;
    const float* xb3 = X + 3*XP + kg*256 + w*32;
    const float* wl  = WL + (w*32)*64 + lane;
    float a0 = 0.f, a1 = 0.f, a2 = 0.f, a3 = 0.f;
#pragma unroll 4
    for (int kk = 0; kk < 32; kk += 4) {
      float4 x0 = *(const float4*)(xb0 + kk);
      float4 x1 = *(const float4*)(xb1 + kk);
      float4 x2 = *(const float4*)(xb2 + kk);
      float4 x3 = *(const float4*)(xb3 + kk);
      float w0 = wl[(kk+0)*64], w1 = wl[(kk+1)*64], w2 = wl[(kk+2)*64], w3 = wl[(kk+3)*64];
      a0 += x0.x*w0 + x0.y*w1 + x0.z*w2 + x0.w*w3;
      a1 += x1.x*w0 + x1.y*w1 + x1.z*w2 + x1.w*w3;
      a2 += x2.x*w0 + x2.y*w1 + x2.z*w2 + x2.w*w3;
      a3 += x3.x*w0 + x3.y*w1 + x3.z*w2 + x3.w*w3;
    }
    RED[w*256 +   0 + lane] = a0;
    RED[w*256 +  64 + lane] = a1;
    RED[w*256 + 128 + lane] = a2;
    RED[w*256 + 192 + lane] = a3;
  }
  __syncthreads();
  if (t < 256) {
    int m = t >> 6, lane = t & 63;
    float v = 0.f;
#pragma unroll
    for (int w = 0; w < 8; w++) v += RED[w*256 + m*64 + lane];
    astore(&prm.qkvp[(size_t)kg*(BB*1536) + (size_t)(g + 4*m)*1536 + mat*DD + (cb & 7)*64 + lane], v);
  }
}

// ---------------------------------------------------------------------------
// ATTN + fused O-proj (Wo tile prefetched). Reduce qkvp (+bias); ch==0 writes
// Kc/Vc[p]; KV history read via ALOAD, staged to LDS with all 512 threads
// (coalesced; amortizes fabric latency across 8 waves). softmax -> ctx ->
// oproj (2-way K-split over 512 thr) -> atomicAdd sA. Group-local zeroing
// of f1 (128/WG) and sB (32/WG).
// ---------------------------------------------------------------------------
__device__ __forceinline__ void attn_stage(const P& prm, int p, int l, float* SH) {
  const int wg = blockIdx.x, t = threadIdx.x;
  const int g = (wg >> 3) & 3;
  const int lid = (wg & 7) + 8 * (wg >> 5);
  const int T16 = (wg & 7) + 8 * ((wg >> 5) & 1);
  const int h = T16 >> 1, ch = T16 & 1;
  const int b = g + 4 * (wg >> 6);
  float* QV  = SH;           // 64
  float* KN  = SH + 64;      // 64
  float* VN  = SH + 128;     // 64
  float* CV  = SH + 192;     // 64
  float* AW  = SH + 256;     // 32
  float* LK  = SH + 288;     // 32*KLS
  float* LV  = LK + 32*KLS;  // 32*KLS (ends 4448)
  float* RED = SH + 288;     // 512 (reuses LK after ctx)
  float* WL2 = SH + WOFF;    // 64x256

  {  // group-local f1 zero: 64 WGs x 128 = group's 4 batches x 2048
    const int br = lid >> 4, chunk = lid & 15;
    if (t < 128) astore(&prm.f1[(size_t)(g + 4*br)*DFF + chunk*128 + t], 0.f);
    // group-local sB zero: 64 WGs x 32 = group's 4 batches x 512
    if (t >= 256 && t < 288)
      astore(&prm.sB[(size_t)(g + 4*br)*DD + chunk*32 + (t-256)], 0.f);
  }
  if (t < 192) {
    int mat = t >> 6, d = t & 63;
    int gc = mat*DD + h*DHH + d;
    float v = aload(&prm.qkvp[(size_t)b*1536 + gc])
            + aload(&prm.qkvp[(size_t)BB*1536 + (size_t)b*1536 + gc])
            + ((mat == 0) ? prm.bq : (mat == 1) ? prm.bk : prm.bv)[l*DD + h*DHH + d];
    if (mat == 0) QV[d] = v;
    else if (mat == 1) { KN[d] = v; if (ch == 0) astore(&prm.Kc[KVIDX(l,b,p) + h*DHH + d], v); }
    else               { VN[d] = v; if (ch == 0) astore(&prm.Vc[KVIDX(l,b,p) + h*DHH + d], v); }
  }
  __syncthreads();
  for (int idx = t; idx < (p+1)*64; idx += NT) {
    int j = idx >> 6, d = idx & 63;
    LK[j*KLS + d] = (j < p) ? aload(&prm.Kc[KVIDX(l,b,j) + h*DHH + d]) : KN[d];
    LV[j*KLS + d] = (j < p) ? aload(&prm.Vc[KVIDX(l,b,j) + h*DHH + d]) : VN[d];
  }
  __syncthreads();
  if (t < 64) {
    int j = t;
    float sc = -1e30f;
    if (j <= p) {
      float s = 0.f;
#pragma unroll 16
      for (int d = 0; d < DHH; d++) s += QV[d] * LK[j*KLS + d];
      sc = s * 0.125f;  // 1/sqrt(64)
    }
    float mx = sc;
#pragma unroll
    for (int m = 32; m >= 1; m >>= 1) mx = fmaxf(mx, __shfl_xor(mx, m));
    float e = (j <= p) ? __expf(sc - mx) : 0.f;
    float den = e;
#pragma unroll
    for (int m = 32; m >= 1; m >>= 1) den += __shfl_xor(den, m);
    if (j < 32) AW[j] = (j <= p) ? (e / den) : 0.f;
  }
  __syncthreads();
  if (t < 64) {
    float a = 0.f;
    for (int j = 0; j <= p; j++) a += AW[j] * LV[j*KLS + t];
    CV[t] = a;
  }
  __syncthreads();
  {  // oproj: col = ch*256 + (t&255), K half = t>>8 (32 each)
    const int c = t & 255, kh = t >> 8;
    const float* wp = WL2 + (kh*32)*256 + c;
    const float* cv = CV + kh*32;
    float a = 0.f;
#pragma unroll 8
    for (int k = 0; k < 32; k++) a += cv[k] * wp[k*256];
    RED[t] = a;
  }
  __syncthreads();
  if (t < 256)
    atomicAdd(&prm.sA[(size_t)b*DD + ch*256 + t], RED[t] + RED[t + 256]);
}

// ---------------------------------------------------------------------------
// FFN1 (W1 tile prefetched). X = LN1(sA); lid==0 publishes ln1x;
// 8-wave GEMM -> atomicAdd f1 (zeroed group-locally in attn).
// ---------------------------------------------------------------------------
__device__ __forceinline__ void ffn1_stage(const P& prm, int l, float* SH) {
  const int wg = blockIdx.x, t = threadIdx.x;
  const int g = (wg >> 3) & 3;
  const int lid = (wg & 7) + 8 * (wg >> 5);
  const int cb = lid >> 1, kg = lid & 1;
  float* X   = SH;            // 2080
  float* RED = SH + 2080;     // 2048
  float* MV  = SH + 4128;     // 8
  float* WL  = SH + WOFF;     // 16384
  for (int idx = t; idx < 4*DD; idx += NT) {
    int r = idx >> 9, i = idx & 511;
    X[r*XP + i] = aload(&prm.sA[(size_t)(g + 4*r)*DD + i]);
  }
  __syncthreads();
  ln_stats4(X, MV, t);
  __syncthreads();
  const float* gm = prm.ln1s + l*DD;
  const float* be = prm.ln1b + l*DD;
  for (int idx = t; idx < 4*DD; idx += NT) {
    int r = idx >> 9, i = idx & 511;
    X[r*XP + i] = (X[r*XP + i] - MV[r*2]) * MV[r*2+1] * gm[i] + be[i];
  }
  __syncthreads();
  if (lid == 0) {
    for (int idx = t; idx < 4*DD; idx += NT) {
      int r = idx >> 9, i = idx & 511;
      astore(&prm.ln1x[(size_t)(g + 4*r)*DD + i], X[r*XP + i]);
    }
  }
  {
    const int w = t >> 6, lane = t & 63;
    const float* xb0 = X + 0*XP + kg*256 + w*32;
    const float* xb1 = X + 1*XP + kg*256 + w*32;
    const float* xb2 = X + 2*XP + kg*256 + w*32;
    const float* xb3 = X + 3*XP + kg*256 + w*32;
    const float* wl  = WL + (w*32)*64 + lane;
    float a0 = 0.f, a1 = 0.f, a2 = 0.f, a3 = 0.f;
#pragma unroll 4
    for (int kk = 0; kk < 32; kk += 4) {
      float4 x0 = *(const float4*)(xb0 + kk);
      float4 x1 = *(const float4*)(xb1 + kk);
      float4 x2 = *(const float4*)(xb2 + kk);
      float4 x3 = *(const float4*)(xb3 + kk);
      float w0 = wl[(kk+0)*64], w1 = wl[(kk+1)*64], w2 = wl[(kk+2)*64], w3 = wl[(kk+3)*64];
      a0 += x0.x*w0 + x0.y*w1 + x0.z*w2 + x0.w*w3;
      a1 += x1.x*w0 + x1.y*w1 + x1.z*w2 + x1.w*w3;
      a2 += x2.x*w0 + x2.y*w1 + x2.z*w2 + x2.w*w3;
      a3 += x3.x*w0 + x3.y*w1 + x3.z*w2 + x3.w*w3;
    }
    RED[w*256 +   0 + lane] = a0;
    RED[w*256 +  64 + lane] = a1;
    RED[w*256 + 128 + lane] = a2;
    RED[w*256 + 192 + lane] = a3;
  }
  __syncthreads();
  if (t < 256) {
    int m = t >> 6, lane = t & 63;
    float v = 0.f;
#pragma unroll
    for (int w = 0; w < 8; w++) v += RED[w*256 + m*64 + lane];
    atomicAdd(&prm.f1[(size_t)(g + 4*m)*DFF + cb*64 + lane], v);
  }
}

// ---------------------------------------------------------------------------
// FFN2 (W2 tile prefetched). FX = relu(f1+b1); 8-wave GEMM -> atomicAdd sB
// (+ln1x+b2 at kg==0).
// ---------------------------------------------------------------------------
__device__ __forceinline__ void ffn2_stage(const P& prm, int l, float* SH) {
  const int wg = blockIdx.x, t = threadIdx.x;
  const int g = (wg >> 3) & 3;
  const int lid = (wg & 7) + 8 * (wg >> 5);
  const int cb = lid >> 3, kg = lid & 7;
  float* FX  = SH;            // 4*XP2 = 1056
  float* RED = SH + 1056;     // 2048
  float* WL  = SH + WOFF;     // 16384
  for (int idx = t; idx < 4*256; idx += NT) {
    int r = idx >> 8, i = idx & 255;
    FX[r*XP2 + i] = fmaxf(aload(&prm.f1[(size_t)(g + 4*r)*DFF + kg*256 + i])
                          + prm.b1[l*DFF + kg*256 + i], 0.f);
  }
  __syncthreads();
  {
    const int w = t >> 6, lane = t & 63;
    const float* x0p = FX + 0*XP2 + w*32;
    const float* x1p = FX + 1*XP2 + w*32;
    const float* x2p = FX + 2*XP2 + w*32;
    const float* x3p = FX + 3*XP2 + w*32;
    const float* wl  = WL + (w*32)*64 + lane;
    float a0 = 0.f, a1 = 0.f, a2 = 0.f, a3 = 0.f;
#pragma unroll 4
    for (int kk = 0; kk < 32; kk += 4) {
      float4 x0 = *(const float4*)(x0p + kk);
      float4 x1 = *(const float4*)(x1p + kk);
      float4 x2 = *(const float4*)(x2p + kk);
      float4 x3 = *(const float4*)(x3p + kk);
      float w0 = wl[(kk+0)*64], w1 = wl[(kk+1)*64], w2 = wl[(kk+2)*64], w3 = wl[(kk+3)*64];
      a0 += x0.x*w0 + x0.y*w1 + x0.z*w2 + x0.w*w3;
      a1 += x1.x*w0 + x1.y*w1 + x1.z*w2 + x1.w*w3;
      a2 += x2.x*w0 + x2.y*w1 + x2.z*w2 + x2.w*w3;
      a3 += x3.x*w0 + x3.y*w1 + x3.z*w2 + x3.w*w3;
    }
    RED[w*256 +   0 + lane] = a0;
    RED[w*256 +  64 + lane] = a1;
    RED[w*256 + 128 + lane] = a2;
    RED[w*256 + 192 + lane] = a3;
  }
  __syncthreads();
  if (t < 256) {
    int m = t >> 6, lane = t & 63;
    float v = 0.f;
#pragma unroll
    for (int w = 0; w < 8; w++) v += RED[w*256 + m*64 + lane];
    int c = cb*64 + lane;
    if (kg == 0) v += aload(&prm.ln1x[(size_t)(g + 4*m)*DD + c]) + prm.b2[l*DD + c];
    atomicAdd(&prm.sB[(size_t)(g + 4*m)*DD + c], v);
  }
}

// ---------------------------------------------------------------------------
// FINAL: out row 30 = LN2_3(sB)@Wf + bf. Per-group: lid<4 handles batch
// b = g + 4*lid (group-local — safe under drift).
// ---------------------------------------------------------------------------
__device__ __forceinline__ void final_stage(const P& prm) {
  const int wg = blockIdx.x, t = threadIdx.x;
  const int g = (wg >> 3) & 3;
  const int lid = (wg & 7) + 8 * (wg >> 5);
  if (lid >= 4 || t >= 64) return;
  const int b = g + 4*lid;
  float v[8];
  float s = 0.f, q = 0.f;
#pragma unroll
  for (int j = 0; j < 8; j++) {
    float x = aload(&prm.sB[(size_t)b*DD + t + j*64]);
    v[j] = x; s += x; q += x*x;
  }
#pragma unroll
  for (int m = 32; m >= 1; m >>= 1) { s += __shfl_xor(s, m); q += __shfl_xor(q, m); }
  const float mu = s * (1.f/DD);
  const float rs = rsqrtf(fmaxf(q * (1.f/DD) - mu*mu, 0.f) + 1e-5f);
  const float* gm = prm.ln2s + 3*DD;
  const float* be = prm.ln2b + 3*DD;
  float po[8];
#pragma unroll
  for (int oc = 0; oc < 8; oc++) po[oc] = 0.f;
#pragma unroll
  for (int j = 0; j < 8; j++) {
    const int i = t + j*64;
    const float x = (v[j] - mu) * rs * gm[i] + be[i];
#pragma unroll
    for (int oc = 0; oc < 8; oc++) po[oc] += x * prm.Wf[i*DOUTC + oc];
  }
#pragma unroll
  for (int m = 32; m >= 1; m >>= 1) {
#pragma unroll
    for (int oc = 0; oc < 8; oc++) po[oc] += __shfl_xor(po[oc], m);
  }
  if (t < 8) prm.out[((size_t)b*TT + 30)*DOUTC + t] = po[t] + prm.bf[t];
}

// ---------------------------------------------------------------------------
__global__ void __launch_bounds__(NT, 1) k_all(P prm) {
  __shared__ __align__(16) float SH[WOFF + 16384];   // 83.5 KB
  const int wg = blockIdx.x, t = threadIdx.x;
  const int g = (wg >> 3) & 3;
  unsigned rnd = 0;
  dma_proj(prm, 0, SH, wg, t);          // prefetch first proj weights
  for (int p = 0; p < TT; p++) {
    for (int l = 0; l < LLAYERS; l++) {
      proj_stage(prm, p, l, SH);
      arrive(prm.bar, g); dma_attn(prm, l, SH, wg, t); waitrnd(prm.bar, g, ++rnd);
      attn_stage(prm, p, l, SH);
      arrive(prm.bar, g); dma_ffn1(prm, l, SH, wg, t); waitrnd(prm.bar, g, ++rnd);
      ffn1_stage(prm, l, SH);
      arrive(prm.bar, g); dma_ffn2(prm, l, SH, wg, t); waitrnd(prm.bar, g, ++rnd);
      ffn2_stage(prm, l, SH);
      const int nl = (l < LLAYERS-1) ? l+1 : 0;
      arrive(prm.bar, g); dma_proj(prm, nl, SH, wg, t); waitrnd(prm.bar, g, ++rnd);
    }
  }
  final_stage(prm);
}

// ---------------------------------------------------------------------------
extern "C" void kernel_launch(void* const* d_in, const int* in_sizes, int n_in,
                              void* d_out, int out_size, void* d_ws, size_t ws_size,
                              hipStream_t stream) {
  (void)in_sizes; (void)n_in; (void)out_size; (void)ws_size;
  P prm;
  prm.seq  = (const float*)d_in[0];
  prm.pe   = (const float*)d_in[1];
  prm.Wt   = (const float*)d_in[2];
  prm.bt   = (const float*)d_in[3];
  prm.Wq   = (const float*)d_in[4];
  prm.bq   = (const float*)d_in[5];
  prm.Wk   = (const float*)d_in[6];
  prm.bk   = (const float*)d_in[7];
  prm.Wv   = (const float*)d_in[8];
  prm.bv   = (const float*)d_in[9];
  prm.Wo   = (const float*)d_in[10];
  prm.bo   = (const float*)d_in[11];
  prm.ln1s = (const float*)d_in[12];
  prm.ln1b = (const float*)d_in[13];
  prm.W1   = (const float*)d_in[14];
  prm.b1   = (const float*)d_in[15];
  prm.W2   = (const float*)d_in[16];
  prm.b2   = (const float*)d_in[17];
  prm.ln2s = (const float*)d_in[18];
  prm.ln2b = (const float*)d_in[19];
  prm.Wf   = (const float*)d_in[20];
  prm.bf   = (const float*)d_in[21];

  float* ws = (float*)d_ws;
  const size_t KSZ = (size_t)LLAYERS * BB * TT * DD;   // ~1.02M floats
  prm.Kc   = ws;
  prm.Vc   = prm.Kc   + KSZ;
  prm.qkvp = prm.Vc   + KSZ;                 // 2*16*1536 = 49152
  prm.sA   = prm.qkvp + 2*BB*1536;           // 8192
  prm.sB   = prm.sA   + BB*DD;               // 8192
  prm.ln1x = prm.sB   + BB*DD;               // 8192
  prm.f1   = prm.ln1x + BB*DD;               // 32768
  prm.bar  = (unsigned*)(prm.f1 + BB*DFF);
  prm.out  = (float*)d_out;

  hipMemsetAsync((void*)prm.bar, 0, 8192, stream);
  hipLaunchKernelGGL(k_all, dim3(NWG), dim3(NT), 0, stream, prm);
}

// Round 18
// 2058.511 us; speedup vs baseline: 1.3538x; 1.1636x over previous
//
#include <hip/hip_runtime.h>
#include <math.h>

#define BB 16
#define SS 32
#define DIN 8
#define DD 512
#define DOUTC 8
#define LLAYERS 4
#define HH 8
#define DFF 2048
#define DHH 64
#define TT 31       // positions produced (S-1)
#define NWG 256     // persistent grid: 256 WGs x 512 threads (2 waves/SIMD)
#define NT 512
#define XP 520      // padded stride for [4][512] LDS rows (float4-aligned)
#define XP2 264     // padded stride for [4][256]
#define KLS 65      // LDS row stride for attn K/V tiles (conflict-free)
#define WOFF 4480   // LDS offset (floats) of the 64KB weight tile

// 4 independent batch-groups: group g = (wg>>3)&3 owns batches {g,g+4,g+8,g+12}.
// All mutable buffers are batch-indexed => zero cross-group sharing; each group
// has its own 64-arrival barrier and drifts freely.

typedef float v2f __attribute__((ext_vector_type(2)));

struct P {
  const float *seq,*pe,*Wt,*bt,*Wq,*bq,*Wk,*bk,*Wv,*bv,*Wo,*bo,
              *ln1s,*ln1b,*W1,*b1,*W2,*b2,*ln2s,*ln2b,*Wf,*bf;
  float *Kc,*Vc,*qkvp,*sA,*sB,*ln1x,*f1,*out;
  unsigned *bar;
};

#define KVIDX(l,b,j) ((((size_t)((l)*BB+(b)))*TT + (j)) * DD)

// ---------------------------------------------------------------------------
// Coherent (cache-bypassing, fabric-serialized) accessors — ALL compiler-
// generated (correct scope bits + waitcnt tracking; the r16/r17 inline-asm
// variants corrupted data). 64-bit pair variants halve fabric request count
// on the staging paths.
// ---------------------------------------------------------------------------
__device__ __forceinline__ float aload(const float* p) {
  return __hip_atomic_load(p, __ATOMIC_RELAXED, __HIP_MEMORY_SCOPE_AGENT);
}
__device__ __forceinline__ void astore(float* p, float v) {
  __hip_atomic_store(p, v, __ATOMIC_RELAXED, __HIP_MEMORY_SCOPE_AGENT);
}
__device__ __forceinline__ unsigned uload(const unsigned* p) {
  return __hip_atomic_load(p, __ATOMIC_RELAXED, __HIP_MEMORY_SCOPE_AGENT);
}
__device__ __forceinline__ v2f aload2(const float* p) {
  unsigned long long u = __hip_atomic_load((const unsigned long long*)p,
      __ATOMIC_RELAXED, __HIP_MEMORY_SCOPE_AGENT);
  union { unsigned long long u; v2f f; } c; c.u = u; return c.f;
}
__device__ __forceinline__ void astore2(float* p, v2f v) {
  union { unsigned long long u; v2f f; } c; c.f = v;
  __hip_atomic_store((unsigned long long*)p, c.u,
      __ATOMIC_RELAXED, __HIP_MEMORY_SCOPE_AGENT);
}

// ---------------------------------------------------------------------------
// Per-group split barrier: 64 arrivals over 8 spread counters (8 each).
// arrive() = syncthreads (drains vmcnt => stores at fabric) + 1 relaxed RMW.
// waitrnd(): lanes 0-7 read-poll the group's 8 counters. Zeroed at launch.
// ---------------------------------------------------------------------------
__device__ __forceinline__ void arrive(unsigned* bar, int g) {
  __syncthreads();
  if (threadIdx.x == 0)
    __hip_atomic_fetch_add(&bar[32 + (g*8 + (blockIdx.x & 7)) * 32], 1u,
                           __ATOMIC_RELAXED, __HIP_MEMORY_SCOPE_AGENT);
}
__device__ __forceinline__ void waitrnd(unsigned* bar, int g, unsigned rnd) {
  if (threadIdx.x < 8) {
    while (uload(&bar[32 + (g*8 + threadIdx.x) * 32]) < rnd * 8u)
      __builtin_amdgcn_s_sleep(1);
  }
  asm volatile("" ::: "memory");
  __syncthreads();
}

// ---------------------------------------------------------------------------
// Async global->LDS DMA, 16B/lane (global_load_lds_dwordx4).
// ---------------------------------------------------------------------------
__device__ __forceinline__ void g2l16(const float* g, float* l) {
  __builtin_amdgcn_global_load_lds(
      (const __attribute__((address_space(1))) void*)g,
      (__attribute__((address_space(3))) void*)l, 16, 0, 0);
}

// 256-row x 64-col fp32 tile (64KB) -> WL[256][64] linear. 8 waves.
__device__ __forceinline__ void stage_w(const float* gbase, size_t rstride,
                                        float* WL, int t) {
  const int wv = t >> 6, ln = t & 63;
  const int rr = ln >> 4, c4 = (ln & 15) * 4;
  const float* g0 = gbase + (size_t)rr * rstride + c4;
  for (int i = wv; i < 64; i += 8)
    g2l16(g0 + (size_t)(i * 4) * rstride, WL + i * 256);
}

// 64-row x 256-col fp32 tile (64KB) -> WL[64][256] linear (row stride DD).
__device__ __forceinline__ void stage_w64(const float* gbase, float* WL, int t) {
  const int wv = t >> 6, ln = t & 63;
  const float* g0 = gbase + ln * 4;
  for (int i = wv; i < 64; i += 8)
    g2l16(g0 + (size_t)i * DD, WL + i * 256);
}

// ---------------------------------------------------------------------------
// Group-local tile id: lid = (wg&7) + 8*(wg>>5) in [0,64). wg&7 = XCD residue
// (all replicas of a tile across groups share it -> tile lives in one L2).
// ---------------------------------------------------------------------------
__device__ __forceinline__ void dma_proj(const P& prm, int l, float* SH, int wg, int t) {
  const int lid = (wg & 7) + 8 * (wg >> 5);
  if (lid >= 48) return;
  const int cb = lid >> 1, kg = lid & 1;
  const int mat = cb >> 3, colb = cb & 7;
  const float* wbase = ((mat == 0) ? prm.Wq : (mat == 1) ? prm.Wk : prm.Wv)
                       + (size_t)l*DD*DD + (size_t)(kg*256)*DD + colb*64;
  stage_w(wbase, DD, SH + WOFF, t);
}
__device__ __forceinline__ void dma_attn(const P& prm, int l, float* SH, int wg, int t) {
  const int T16 = (wg & 7) + 8 * ((wg >> 5) & 1);
  const int h = T16 >> 1, ch = T16 & 1;
  stage_w64(prm.Wo + (size_t)l*DD*DD + (size_t)(h*DHH)*DD + ch*256, SH + WOFF, t);
}
__device__ __forceinline__ void dma_ffn1(const P& prm, int l, float* SH, int wg, int t) {
  const int lid = (wg & 7) + 8 * (wg >> 5);
  const int cb = lid >> 1, kg = lid & 1;
  stage_w(prm.W1 + (size_t)l*DD*DFF + (size_t)(kg*256)*DFF + cb*64, DFF, SH + WOFF, t);
}
__device__ __forceinline__ void dma_ffn2(const P& prm, int l, float* SH, int wg, int t) {
  const int lid = (wg & 7) + 8 * (wg >> 5);
  const int cb = lid >> 3, kg = lid & 7;
  stage_w(prm.W2 + (size_t)l*DFF*DD + (size_t)(kg*256)*DD + cb*64, DD, SH + WOFF, t);
}

// ---------------------------------------------------------------------------
// LN stats: X holds 4 rows at stride XP; first 4 waves -> one row each.
// ---------------------------------------------------------------------------
__device__ __forceinline__ void ln_stats4(const float* X, float* MV, int t) {
  if (t < 256) {
    int r = t >> 6, ln = t & 63;
    float s = 0.f, q = 0.f;
    for (int i = ln; i < DD; i += 64) { float v = X[r*XP + i]; s += v; q += v*v; }
#pragma unroll
    for (int m = 32; m >= 1; m >>= 1) { s += __shfl_xor(s, m); q += __shfl_xor(q, m); }
    if (ln == 0) {
      float mu = s * (1.f/DD);
      MV[r*2]   = mu;
      MV[r*2+1] = rsqrtf(fmaxf(q * (1.f/DD) - mu*mu, 0.f) + 1e-5f);
    }
  }
}

// ---------------------------------------------------------------------------
// PROJ (weights prefetched). Rows r=0..3 -> batch g+4r. X = LN2(sB) or
// head+embed. lid==0 publishes sA = x + bo and out row. 8-wave GEMM ->
// qkvp[kg] complete per (kg, batch, col).
// ---------------------------------------------------------------------------
__device__ __forceinline__ void proj_stage(const P& prm, int p, int l, float* SH) {
  const int wg = blockIdx.x, t = threadIdx.x;
  const int g = (wg >> 3) & 3;
  const int lid = (wg & 7) + 8 * (wg >> 5);
  if (lid >= 48) return;
  const int cb = lid >> 1, kg = lid & 1;
  const int mat = cb >> 3;
  float* X   = SH;            // 2080
  float* RED = SH + 2080;     // 2048
  float* YP  = SH + 4128;     // 256
  float* YS  = SH + 4384;     // 32
  float* MV  = SH + 4416;     // 8
  float* WL  = SH + WOFF;     // 16384

  if (l > 0 || p > 0) {
    for (int idx = t; idx < 1024; idx += NT) {   // 1024 pairs = 4 rows x 512
      int r = idx >> 8, ip = (idx & 255) * 2;
      v2f v = aload2(&prm.sB[(size_t)(g + 4*r)*DD + ip]);
      X[r*XP + ip]     = v.x;
      X[r*XP + ip + 1] = v.y;
    }
    __syncthreads();
    ln_stats4(X, MV, t);
    __syncthreads();
    const int pl = (l > 0) ? (l - 1) : 3;
    const float* gm = prm.ln2s + pl*DD;
    const float* be = prm.ln2b + pl*DD;
    for (int idx = t; idx < 4*DD; idx += NT) {
      int r = idx >> 9, i = idx & 511;
      X[r*XP + i] = (X[r*XP + i] - MV[r*2]) * MV[r*2+1] * gm[i] + be[i];
    }
    __syncthreads();
  }
  if (l == 0) {
    if (p == 0) {
      if (t < 32) { int r = t>>3, c = t&7; YS[r*8 + c] = prm.seq[(size_t)(g + 4*r)*SS*DIN + c]; }
      __syncthreads();
    } else {
      if (t < 256) { // y = LN2_3(sB) @ Wf + bf (X holds LN'd rows)
        int r = t >> 6, oc = (t >> 3) & 7, ks = t & 7;
        float a = 0.f;
        const float* xr = X + r*XP + ks*64;
#pragma unroll 8
        for (int i = 0; i < 64; i++) a += xr[i] * prm.Wf[(ks*64 + i)*DOUTC + oc];
        YP[t] = a;
      }
      __syncthreads();
      if (t < 32) {
        int r = t>>3, oc = t&7;
        float yv = prm.bf[oc];
#pragma unroll
        for (int k = 0; k < 8; k++) yv += YP[r*64 + oc*8 + k];
        YS[r*8 + oc] = yv;
        if (lid == 0)
          prm.out[((size_t)(g + 4*r)*TT + (p-1))*DOUTC + oc] = yv;
      }
      __syncthreads();
    }
    for (int idx = t; idx < 4*DD; idx += NT) {
      int r = idx >> 9, i = idx & 511;
      float a = prm.bt[i] + prm.pe[(size_t)p*DD + i];
#pragma unroll
      for (int k = 0; k < 8; k++) a += YS[r*8 + k] * prm.Wt[k*DD + i];
      X[r*XP + i] = a;
    }
    __syncthreads();
  }
  if (lid == 0) {   // sA base = x + bo (attn atomically adds oproj)
    for (int idx = t; idx < 1024; idx += NT) {
      int r = idx >> 8, ip = (idx & 255) * 2;
      v2f xv; xv.x = X[r*XP + ip]; xv.y = X[r*XP + ip + 1];
      v2f bo2; bo2.x = prm.bo[l*DD + ip]; bo2.y = prm.bo[l*DD + ip + 1];
      astore2(&prm.sA[(size_t)(g + 4*r)*DD + ip], xv + bo2);
    }
  }
  // 8-wave GEMM from LDS: wave w -> K rows w*32..w*32+31 of the 256-row tile
  {
    const int w = t >> 6, lane = t & 63;
    const float* xb0 = X + 0*XP + kg*256 + w*32;
    const float* xb1 = X + 1*XP + kg*256 + w*32;
    const float* xb2 = X + 2*XP + kg*256 + w*32;
    const float* xb3 = X + 3*XP + kg*256 + w*32;
    const float* wl  = WL + (w*32)*64 + lane;
    float a0 = 0.f, a1 = 0.f, a2 = 0.f, a3 = 0.f;
#pragma unroll 4
    for (int kk = 0; kk < 32; kk += 4) {
      float4 x0 = *(const float4*)(xb0 + kk);
      float4 x1 = *(const float4*)(xb1 + kk);
      float4 x2 = *(const float4*)(xb2 + kk);
      float4 x3 = *(const float4*)(xb3 + kk);
      float w0 = wl[(kk+0)*64], w1 = wl[(kk+1)*64], w2 = wl[(kk+2)*64], w3 = wl[(kk+3)*64];
      a0 += x0.x*w0 + x0.y*w1 + x0.z*w2 + x0.w*w3;
      a1 += x1.x*w0 + x1.y*w1 + x1.z*w2 + x1.w*w3;
      a2 += x2.x*w0 + x2.y*w1 + x2.z*w2 + x2.w*w3;
      a3 += x3.x*w0 + x3.y*w1 + x3.z*w2 + x3.w*w3;
    }
    RED[w*256 +   0 + lane] = a0;
    RED[w*256 +  64 + lane] = a1;
    RED[w*256 + 128 + lane] = a2;
    RED[w*256 + 192 + lane] = a3;
  }
  __syncthreads();
  if (t < 256) {
    int m = t >> 6, lane = t & 63;
    float v = 0.f;
#pragma unroll
    for (int w = 0; w < 8; w++) v += RED[w*256 + m*64 + lane];
    astore(&prm.qkvp[(size_t)kg*(BB*1536) + (size_t)(g + 4*m)*1536 + mat*DD + (cb & 7)*64 + lane], v);
  }
}

// ---------------------------------------------------------------------------
// ATTN + fused O-proj (Wo tile prefetched). Reduce qkvp (+bias); ch==0 writes
// Kc/Vc[p]; KV history read via PAIRED coherent loads, staged to LDS with
// all 512 threads (amortizes fabric latency across 8 waves; r14 layouts).
// softmax -> ctx -> oproj (2-way K-split over 512 thr) -> atomicAdd sA.
// Group-local zeroing of f1 (128/WG) and sB (32/WG).
// ---------------------------------------------------------------------------
__device__ __forceinline__ void attn_stage(const P& prm, int p, int l, float* SH) {
  const int wg = blockIdx.x, t = threadIdx.x;
  const int g = (wg >> 3) & 3;
  const int lid = (wg & 7) + 8 * (wg >> 5);
  const int T16 = (wg & 7) + 8 * ((wg >> 5) & 1);
  const int h = T16 >> 1, ch = T16 & 1;
  const int b = g + 4 * (wg >> 6);
  float* QV  = SH;           // 64
  float* KN  = SH + 64;      // 64
  float* VN  = SH + 128;     // 64
  float* CV  = SH + 192;     // 64
  float* AW  = SH + 256;     // 32
  float* LK  = SH + 288;     // 32*KLS
  float* LV  = LK + 32*KLS;  // 32*KLS (ends 4448)
  float* RED = SH + 288;     // 512 (reuses LK after ctx)
  float* WL2 = SH + WOFF;    // 64x256

  {  // group-local f1 zero: 64 WGs x 128 = group's 4 batches x 2048
    const int br = lid >> 4, chunk = lid & 15;
    if (t < 128) astore(&prm.f1[(size_t)(g + 4*br)*DFF + chunk*128 + t], 0.f);
    // group-local sB zero: 64 WGs x 32 = group's 4 batches x 512
    if (t >= 256 && t < 288)
      astore(&prm.sB[(size_t)(g + 4*br)*DD + chunk*32 + (t-256)], 0.f);
  }
  if (t < 192) {
    int mat = t >> 6, d = t & 63;
    int gc = mat*DD + h*DHH + d;
    float v = aload(&prm.qkvp[(size_t)b*1536 + gc])
            + aload(&prm.qkvp[(size_t)BB*1536 + (size_t)b*1536 + gc])
            + ((mat == 0) ? prm.bq : (mat == 1) ? prm.bk : prm.bv)[l*DD + h*DHH + d];
    if (mat == 0) QV[d] = v;
    else if (mat == 1) { KN[d] = v; if (ch == 0) astore(&prm.Kc[KVIDX(l,b,p) + h*DHH + d], v); }
    else               { VN[d] = v; if (ch == 0) astore(&prm.Vc[KVIDX(l,b,p) + h*DHH + d], v); }
  }
  __syncthreads();
  for (int idx = t; idx < (p+1)*32; idx += NT) {
    int j = idx >> 5, d2 = (idx & 31) * 2;
    v2f kv, vv;
    if (j < p) {
      kv = aload2(&prm.Kc[KVIDX(l,b,j) + h*DHH + d2]);
      vv = aload2(&prm.Vc[KVIDX(l,b,j) + h*DHH + d2]);
    } else {
      kv.x = KN[d2]; kv.y = KN[d2 + 1];
      vv.x = VN[d2]; vv.y = VN[d2 + 1];
    }
    LK[j*KLS + d2]     = kv.x;
    LK[j*KLS + d2 + 1] = kv.y;
    LV[j*KLS + d2]     = vv.x;
    LV[j*KLS + d2 + 1] = vv.y;
  }
  __syncthreads();
  if (t < 64) {
    int j = t;
    float sc = -1e30f;
    if (j <= p) {
      float s = 0.f;
#pragma unroll 16
      for (int d = 0; d < DHH; d++) s += QV[d] * LK[j*KLS + d];
      sc = s * 0.125f;  // 1/sqrt(64)
    }
    float mx = sc;
#pragma unroll
    for (int m = 32; m >= 1; m >>= 1) mx = fmaxf(mx, __shfl_xor(mx, m));
    float e = (j <= p) ? __expf(sc - mx) : 0.f;
    float den = e;
#pragma unroll
    for (int m = 32; m >= 1; m >>= 1) den += __shfl_xor(den, m);
    if (j < 32) AW[j] = (j <= p) ? (e / den) : 0.f;
  }
  __syncthreads();
  if (t < 64) {
    float a = 0.f;
    for (int j = 0; j <= p; j++) a += AW[j] * LV[j*KLS + t];
    CV[t] = a;
  }
  __syncthreads();
  {  // oproj: col = ch*256 + (t&255), K half = t>>8 (32 each)
    const int c = t & 255, kh = t >> 8;
    const float* wp = WL2 + (kh*32)*256 + c;
    const float* cv = CV + kh*32;
    float a = 0.f;
#pragma unroll 8
    for (int k = 0; k < 32; k++) a += cv[k] * wp[k*256];
    RED[t] = a;
  }
  __syncthreads();
  if (t < 256)
    atomicAdd(&prm.sA[(size_t)b*DD + ch*256 + t], RED[t] + RED[t + 256]);
}

// ---------------------------------------------------------------------------
// FFN1 (W1 tile prefetched). X = LN1(sA); lid==0 publishes ln1x;
// 8-wave GEMM -> atomicAdd f1 (zeroed group-locally in attn).
// ---------------------------------------------------------------------------
__device__ __forceinline__ void ffn1_stage(const P& prm, int l, float* SH) {
  const int wg = blockIdx.x, t = threadIdx.x;
  const int g = (wg >> 3) & 3;
  const int lid = (wg & 7) + 8 * (wg >> 5);
  const int cb = lid >> 1, kg = lid & 1;
  float* X   = SH;            // 2080
  float* RED = SH + 2080;     // 2048
  float* MV  = SH + 4128;     // 8
  float* WL  = SH + WOFF;     // 16384
  for (int idx = t; idx < 1024; idx += NT) {
    int r = idx >> 8, ip = (idx & 255) * 2;
    v2f v = aload2(&prm.sA[(size_t)(g + 4*r)*DD + ip]);
    X[r*XP + ip]     = v.x;
    X[r*XP + ip + 1] = v.y;
  }
  __syncthreads();
  ln_stats4(X, MV, t);
  __syncthreads();
  const float* gm = prm.ln1s + l*DD;
  const float* be = prm.ln1b + l*DD;
  for (int idx = t; idx < 4*DD; idx += NT) {
    int r = idx >> 9, i = idx & 511;
    X[r*XP + i] = (X[r*XP + i] - MV[r*2]) * MV[r*2+1] * gm[i] + be[i];
  }
  __syncthreads();
  if (lid == 0) {
    for (int idx = t; idx < 1024; idx += NT) {
      int r = idx >> 8, ip = (idx & 255) * 2;
      v2f xv; xv.x = X[r*XP + ip]; xv.y = X[r*XP + ip + 1];
      astore2(&prm.ln1x[(size_t)(g + 4*r)*DD + ip], xv);
    }
  }
  {
    const int w = t >> 6, lane = t & 63;
    const float* xb0 = X + 0*XP + kg*256 + w*32;
    const float* xb1 = X + 1*XP + kg*256 + w*32;
    const float* xb2 = X + 2*XP + kg*256 + w*32;
    const float* xb3 = X + 3*XP + kg*256 + w*32;
    const float* wl  = WL + (w*32)*64 + lane;
    float a0 = 0.f, a1 = 0.f, a2 = 0.f, a3 = 0.f;
#pragma unroll 4
    for (int kk = 0; kk < 32; kk += 4) {
      float4 x0 = *(const float4*)(xb0 + kk);
      float4 x1 = *(const float4*)(xb1 + kk);
      float4 x2 = *(const float4*)(xb2 + kk);
      float4 x3 = *(const float4*)(xb3 + kk);
      float w0 = wl[(kk+0)*64], w1 = wl[(kk+1)*64], w2 = wl[(kk+2)*64], w3 = wl[(kk+3)*64];
      a0 += x0.x*w0 + x0.y*w1 + x0.z*w2 + x0.w*w3;
      a1 += x1.x*w0 + x1.y*w1 + x1.z*w2 + x1.w*w3;
      a2 += x2.x*w0 + x2.y*w1 + x2.z*w2 + x2.w*w3;
      a3 += x3.x*w0 + x3.y*w1 + x3.z*w2 + x3.w*w3;
    }
    RED[w*256 +   0 + lane] = a0;
    RED[w*256 +  64 + lane] = a1;
    RED[w*256 + 128 + lane] = a2;
    RED[w*256 + 192 + lane] = a3;
  }
  __syncthreads();
  if (t < 256) {
    int m = t >> 6, lane = t & 63;
    float v = 0.f;
#pragma unroll
    for (int w = 0; w < 8; w++) v += RED[w*256 + m*64 + lane];
    atomicAdd(&prm.f1[(size_t)(g + 4*m)*DFF + cb*64 + lane], v);
  }
}

// ---------------------------------------------------------------------------
// FFN2 (W2 tile prefetched). FX = relu(f1+b1) via paired coherent loads;
// 8-wave GEMM -> atomicAdd sB (+ln1x+b2 at kg==0).
// ---------------------------------------------------------------------------
__device__ __forceinline__ void ffn2_stage(const P& prm, int l, float* SH) {
  const int wg = blockIdx.x, t = threadIdx.x;
  const int g = (wg >> 3) & 3;
  const int lid = (wg & 7) + 8 * (wg >> 5);
  const int cb = lid >> 3, kg = lid & 7;
  float* FX  = SH;            // 4*XP2 = 1056
  float* RED = SH + 1056;     // 2048
  float* WL  = SH + WOFF;     // 16384
  for (int idx = t; idx < 512; idx += NT) {   // 512 pairs = 4 rows x 256
    int r = idx >> 7, ip = (idx & 127) * 2;
    v2f v = aload2(&prm.f1[(size_t)(g + 4*r)*DFF + kg*256 + ip]);
    FX[r*XP2 + ip]     = fmaxf(v.x + prm.b1[l*DFF + kg*256 + ip], 0.f);
    FX[r*XP2 + ip + 1] = fmaxf(v.y + prm.b1[l*DFF + kg*256 + ip + 1], 0.f);
  }
  __syncthreads();
  {
    const int w = t >> 6, lane = t & 63;
    const float* x0p = FX + 0*XP2 + w*32;
    const float* x1p = FX + 1*XP2 + w*32;
    const float* x2p = FX + 2*XP2 + w*32;
    const float* x3p = FX + 3*XP2 + w*32;
    const float* wl  = WL + (w*32)*64 + lane;
    float a0 = 0.f, a1 = 0.f, a2 = 0.f, a3 = 0.f;
#pragma unroll 4
    for (int kk = 0; kk < 32; kk += 4) {
      float4 x0 = *(const float4*)(x0p + kk);
      float4 x1 = *(const float4*)(x1p + kk);
      float4 x2 = *(const float4*)(x2p + kk);
      float4 x3 = *(const float4*)(x3p + kk);
      float w0 = wl[(kk+0)*64], w1 = wl[(kk+1)*64], w2 = wl[(kk+2)*64], w3 = wl[(kk+3)*64];
      a0 += x0.x*w0 + x0.y*w1 + x0.z*w2 + x0.w*w3;
      a1 += x1.x*w0 + x1.y*w1 + x1.z*w2 + x1.w*w3;
      a2 += x2.x*w0 + x2.y*w1 + x2.z*w2 + x2.w*w3;
      a3 += x3.x*w0 + x3.y*w1 + x3.z*w2 + x3.w*w3;
    }
    RED[w*256 +   0 + lane] = a0;
    RED[w*256 +  64 + lane] = a1;
    RED[w*256 + 128 + lane] = a2;
    RED[w*256 + 192 + lane] = a3;
  }
  __syncthreads();
  if (t < 256) {
    int m = t >> 6, lane = t & 63;
    float v = 0.f;
#pragma unroll
    for (int w = 0; w < 8; w++) v += RED[w*256 + m*64 + lane];
    int c = cb*64 + lane;
    if (kg == 0) v += aload(&prm.ln1x[(size_t)(g + 4*m)*DD + c]) + prm.b2[l*DD + c];
    atomicAdd(&prm.sB[(size_t)(g + 4*m)*DD + c], v);
  }
}

// ---------------------------------------------------------------------------
// FINAL: out row 30 = LN2_3(sB)@Wf + bf. Per-group: lid<4 handles batch
// b = g + 4*lid (group-local — safe under drift).
// ---------------------------------------------------------------------------
__device__ __forceinline__ void final_stage(const P& prm) {
  const int wg = blockIdx.x, t = threadIdx.x;
  const int g = (wg >> 3) & 3;
  const int lid = (wg & 7) + 8 * (wg >> 5);
  if (lid >= 4 || t >= 64) return;
  const int b = g + 4*lid;
  float v[8];
  float s = 0.f, q = 0.f;
#pragma unroll
  for (int j = 0; j < 8; j++) {
    float x = aload(&prm.sB[(size_t)b*DD + t + j*64]);
    v[j] = x; s += x; q += x*x;
  }
#pragma unroll
  for (int m = 32; m >= 1; m >>= 1) { s += __shfl_xor(s, m); q += __shfl_xor(q, m); }
  const float mu = s * (1.f/DD);
  const float rs = rsqrtf(fmaxf(q * (1.f/DD) - mu*mu, 0.f) + 1e-5f);
  const float* gm = prm.ln2s + 3*DD;
  const float* be = prm.ln2b + 3*DD;
  float po[8];
#pragma unroll
  for (int oc = 0; oc < 8; oc++) po[oc] = 0.f;
#pragma unroll
  for (int j = 0; j < 8; j++) {
    const int i = t + j*64;
    const float x = (v[j] - mu) * rs * gm[i] + be[i];
#pragma unroll
    for (int oc = 0; oc < 8; oc++) po[oc] += x * prm.Wf[i*DOUTC + oc];
  }
#pragma unroll
  for (int m = 32; m >= 1; m >>= 1) {
#pragma unroll
    for (int oc = 0; oc < 8; oc++) po[oc] += __shfl_xor(po[oc], m);
  }
  if (t < 8) prm.out[((size_t)b*TT + 30)*DOUTC + t] = po[t] + prm.bf[t];
}

// ---------------------------------------------------------------------------
__global__ void __launch_bounds__(NT, 1) k_all(P prm) {
  __shared__ __align__(16) float SH[WOFF + 16384];   // 83.5 KB
  const int wg = blockIdx.x, t = threadIdx.x;
  const int g = (wg >> 3) & 3;
  unsigned rnd = 0;
  dma_proj(prm, 0, SH, wg, t);          // prefetch first proj weights
  for (int p = 0; p < TT; p++) {
    for (int l = 0; l < LLAYERS; l++) {
      proj_stage(prm, p, l, SH);
      arrive(prm.bar, g); dma_attn(prm, l, SH, wg, t); waitrnd(prm.bar, g, ++rnd);
      attn_stage(prm, p, l, SH);
      arrive(prm.bar, g); dma_ffn1(prm, l, SH, wg, t); waitrnd(prm.bar, g, ++rnd);
      ffn1_stage(prm, l, SH);
      arrive(prm.bar, g); dma_ffn2(prm, l, SH, wg, t); waitrnd(prm.bar, g, ++rnd);
      ffn2_stage(prm, l, SH);
      const int nl = (l < LLAYERS-1) ? l+1 : 0;
      arrive(prm.bar, g); dma_proj(prm, nl, SH, wg, t); waitrnd(prm.bar, g, ++rnd);
    }
  }
  final_stage(prm);
}

// ---------------------------------------------------------------------------
extern "C" void kernel_launch(void* const* d_in, const int* in_sizes, int n_in,
                              void* d_out, int out_size, void* d_ws, size_t ws_size,
                              hipStream_t stream) {
  (void)in_sizes; (void)n_in; (void)out_size; (void)ws_size;
  P prm;
  prm.seq  = (const float*)d_in[0];
  prm.pe   = (const float*)d_in[1];
  prm.Wt   = (const float*)d_in[2];
  prm.bt   = (const float*)d_in[3];
  prm.Wq   = (const float*)d_in[4];
  prm.bq   = (const float*)d_in[5];
  prm.Wk   = (const float*)d_in[6];
  prm.bk   = (const float*)d_in[7];
  prm.Wv   = (const float*)d_in[8];
  prm.bv   = (const float*)d_in[9];
  prm.Wo   = (const float*)d_in[10];
  prm.bo   = (const float*)d_in[11];
  prm.ln1s = (const float*)d_in[12];
  prm.ln1b = (const float*)d_in[13];
  prm.W1   = (const float*)d_in[14];
  prm.b1   = (const float*)d_in[15];
  prm.W2   = (const float*)d_in[16];
  prm.b2   = (const float*)d_in[17];
  prm.ln2s = (const float*)d_in[18];
  prm.ln2b = (const float*)d_in[19];
  prm.Wf   = (const float*)d_in[20];
  prm.bf   = (const float*)d_in[21];

  float* ws = (float*)d_ws;
  const size_t KSZ = (size_t)LLAYERS * BB * TT * DD;   // ~1.02M floats
  prm.Kc   = ws;
  prm.Vc   = prm.Kc   + KSZ;
  prm.qkvp = prm.Vc   + KSZ;                 // 2*16*1536 = 49152
  prm.sA   = prm.qkvp + 2*BB*1536;           // 8192
  prm.sB   = prm.sA   + BB*DD;               // 8192
  prm.ln1x = prm.sB   + BB*DD;               // 8192
  prm.f1   = prm.ln1x + BB*DD;               // 32768
  prm.bar  = (unsigned*)(prm.f1 + BB*DFF);
  prm.out  = (float*)d_out;

  hipMemsetAsync((void*)prm.bar, 0, 8192, stream);
  hipLaunchKernelGGL(k_all, dim3(NWG), dim3(NT), 0, stream, prm);
}